// Round 5
// baseline (167.868 us; speedup 1.0000x reference)
//
#include <hip/hip_runtime.h>
#include <hip/hip_bf16.h>

#define LN_EPS 1e-5f

// ---------------------------------------------------------------------------
// Kernel 1: embed + pos + row attention (64 bins) + residual + LN
// one block per (b, s): 256 blocks x 256 threads
// GEMM lane map: weight row is wave-uniform (broadcast), x row hoisted to regs.
// ---------------------------------------------------------------------------
__global__ __launch_bounds__(256) void k_row(
    const float* __restrict__ ctcf, const float* __restrict__ hac,
    const float* __restrict__ me1,  const float* __restrict__ me3,
    const float* __restrict__ ew,   const float* __restrict__ eb,
    const float* __restrict__ pe,
    const float* __restrict__ w_in, const float* __restrict__ b_in,
    const float* __restrict__ w_out,const float* __restrict__ b_out,
    const float* __restrict__ ln_g, const float* __restrict__ ln_b,
    float* __restrict__ msaR)
{
    __shared__ float sx[64][33];        // x tile (residual source)
    __shared__ float sqkv[64 * 100];    // qkv rows, stride 100 (16B-aligned)
    __shared__ float so[64][33];        // attention output
    __shared__ float swin[96 * 32];     // read broadcast -> no pad needed
    __shared__ float swout[32 * 32];
    __shared__ float sbin[96];
    __shared__ float sbout[32], sg[32], sb[32];
    __shared__ float smean[64], srstd[64];

    const int blk = blockIdx.x;          // b*4 + s
    const int s   = blk & 3;
    const int b   = blk >> 2;
    const int tid = threadIdx.x;

    const float* chip = (s == 0) ? ctcf : (s == 1) ? hac : (s == 2) ? me1 : me3;

    for (int n = tid; n < 96 * 32; n += 256) swin[n] = w_in[n];
    for (int n = tid; n < 32 * 32; n += 256) swout[n] = w_out[n];
    if (tid < 96) sbin[tid] = b_in[tid];
    if (tid < 32) {
        sbout[tid] = b_out[tid];
        sg[tid] = ln_g[tid];
        sb[tid] = ln_b[tid];
    }
    for (int n = tid; n < 2048; n += 256) {
        int l = n >> 5, c = n & 31;
        sx[l][c] = chip[b * 64 + l] * ew[c] + eb[c] + pe[l * 32 + c];
    }
    __syncthreads();

    const int l  = tid & 63;
    const int cg = tid >> 6;             // 0..3 (wave id -> wave-uniform)

    float xr[32];
#pragma unroll
    for (int c = 0; c < 32; ++c) xr[c] = sx[l][c];

    // qkv[l][cc] = x[l]·w_in[cc] + b_in[cc]; lanes share cc -> broadcast w read
#pragma unroll
    for (int i = 0; i < 24; ++i) {
        int cc = i * 4 + cg;
        const float* wr = &swin[cc * 32];
        float acc = sbin[cc];
#pragma unroll
        for (int c = 0; c < 32; ++c) acc += xr[c] * wr[c];
        sqkv[l * 100 + cc] = acc;
    }
    __syncthreads();

    // attention: thread (h = cg, l); online softmax over j (k/v reads broadcast)
    {
        const int h = cg;
        float q[8];
#pragma unroll
        for (int dd = 0; dd < 8; ++dd) q[dd] = sqkv[l * 100 + h * 8 + dd];
        const float scale = 0.35355339059327373f;  // 1/sqrt(8)
        float mrun = -1e30f, denom = 0.f, acc[8];
#pragma unroll
        for (int dd = 0; dd < 8; ++dd) acc[dd] = 0.f;
        for (int j = 0; j < 64; ++j) {
            const float* kr = &sqkv[j * 100 + 32 + h * 8];
            const float* vr = &sqkv[j * 100 + 64 + h * 8];
            float sc = 0.f;
#pragma unroll
            for (int dd = 0; dd < 8; ++dd) sc += q[dd] * kr[dd];
            sc *= scale;
            float mnew = fmaxf(mrun, sc);
            float corr = __expf(mrun - mnew);
            float w = __expf(sc - mnew);
            denom = denom * corr + w;
#pragma unroll
            for (int dd = 0; dd < 8; ++dd)
                acc[dd] = acc[dd] * corr + w * vr[dd];
            mrun = mnew;
        }
        float inv = 1.f / denom;
#pragma unroll
        for (int dd = 0; dd < 8; ++dd) so[l][h * 8 + dd] = acc[dd] * inv;
    }
    __syncthreads();

    // out proj + residual (xr regs) -> write into sqkv cols 0..31
    {
        float orow[32];
#pragma unroll
        for (int k = 0; k < 32; ++k) orow[k] = so[l][k];
#pragma unroll
        for (int i = 0; i < 8; ++i) {
            int c = i * 4 + cg;
            const float* wr = &swout[c * 32];
            float acc = sbout[c] + xr[c];
#pragma unroll
            for (int k = 0; k < 32; ++k) acc += orow[k] * wr[k];
            sqkv[l * 100 + c] = acc;
        }
    }
    __syncthreads();

    if (tid < 64) {
        float mu = 0.f;
#pragma unroll
        for (int c = 0; c < 32; ++c) mu += sqkv[tid * 100 + c];
        mu *= (1.f / 32.f);
        float var = 0.f;
#pragma unroll
        for (int c = 0; c < 32; ++c) { float d = sqkv[tid * 100 + c] - mu; var += d * d; }
        var *= (1.f / 32.f);
        smean[tid] = mu;
        srstd[tid] = rsqrtf(var + LN_EPS);
    }
    __syncthreads();

    float* outp = msaR + blk * 2048;     // (B,S,Lb,C)
    for (int n = tid; n < 2048; n += 256) {
        int ll = n >> 5, c = n & 31;
        outp[n] = (sqkv[ll * 100 + c] - smean[ll]) * srstd[ll] * sg[c] + sb[c];
    }
}

// ---------------------------------------------------------------------------
// Kernel 2: column attention (4 tracks) + residual + LN + track mean + norm
// one block per (b, 16-bin chunk): 256 blocks x 256 threads
// ---------------------------------------------------------------------------
__global__ __launch_bounds__(256) void k_col(
    const float* __restrict__ msaR,
    const float* __restrict__ w_in, const float* __restrict__ b_in,
    const float* __restrict__ w_out,const float* __restrict__ b_out,
    const float* __restrict__ ln_g, const float* __restrict__ ln_b,
    float* __restrict__ m_out, float* __restrict__ nrm_out)
{
    __shared__ float sx[64][33];        // rows keyed s*16+lo
    __shared__ float sqkv[64 * 100];    // rows keyed r = lo*4+s
    __shared__ float so[64][33];        // rows keyed r
    __shared__ float swi[96 * 32];
    __shared__ float swo[32 * 32];
    __shared__ float sbi[96];
    __shared__ float sbo[32], sg[32], sb[32];
    __shared__ float smean2[64], srstd2[64];
    __shared__ float smv[16][33];

    const int bx = blockIdx.x;           // 64 b x 4 chunks
    const int b  = bx >> 2;
    const int l0 = (bx & 3) * 16;
    const int tid = threadIdx.x;

    for (int n = tid; n < 96 * 32; n += 256) swi[n] = w_in[n];
    for (int n = tid; n < 32 * 32; n += 256) swo[n] = w_out[n];
    if (tid < 96) sbi[tid] = b_in[tid];
    if (tid < 32) {
        sbo[tid] = b_out[tid];
        sg[tid] = ln_g[tid];
        sb[tid] = ln_b[tid];
    }
    for (int n = tid; n < 2048; n += 256) {
        int s = n >> 9, lo = (n >> 5) & 15, c = n & 31;
        sx[s * 16 + lo][c] = msaR[((b * 4 + s) * 64 + l0 + lo) * 32 + c];
    }
    __syncthreads();

    const int r  = tid & 63;
    const int sS = r & 3, lo = r >> 2;
    const int cg = tid >> 6;

    float xr[32];
#pragma unroll
    for (int c = 0; c < 32; ++c) xr[c] = sx[sS * 16 + lo][c];

#pragma unroll
    for (int i = 0; i < 24; ++i) {
        int cc = i * 4 + cg;
        const float* wr = &swi[cc * 32];
        float acc = sbi[cc];
#pragma unroll
        for (int c = 0; c < 32; ++c) acc += xr[c] * wr[c];
        sqkv[r * 100 + cc] = acc;
    }
    __syncthreads();

    {
        const int la = tid >> 4, h = (tid >> 2) & 3, ia = tid & 3;
        const float scale = 0.35355339059327373f;
        float q[8];
#pragma unroll
        for (int dd = 0; dd < 8; ++dd) q[dd] = sqkv[(la * 4 + ia) * 100 + h * 8 + dd];
        float sc[4];
        float mx = -1e30f;
#pragma unroll
        for (int jj = 0; jj < 4; ++jj) {
            const float* kr = &sqkv[(la * 4 + jj) * 100 + 32 + h * 8];
            float v = 0.f;
#pragma unroll
            for (int dd = 0; dd < 8; ++dd) v += q[dd] * kr[dd];
            sc[jj] = v * scale;
            mx = fmaxf(mx, sc[jj]);
        }
        float den = 0.f;
#pragma unroll
        for (int jj = 0; jj < 4; ++jj) { sc[jj] = __expf(sc[jj] - mx); den += sc[jj]; }
        float inv = 1.f / den;
#pragma unroll
        for (int dd = 0; dd < 8; ++dd) {
            float a = 0.f;
#pragma unroll
            for (int jj = 0; jj < 4; ++jj)
                a += sc[jj] * sqkv[(la * 4 + jj) * 100 + 64 + h * 8 + dd];
            so[la * 4 + ia][h * 8 + dd] = a * inv;
        }
    }
    __syncthreads();

    {
        float orow[32];
#pragma unroll
        for (int k = 0; k < 32; ++k) orow[k] = so[r][k];
#pragma unroll
        for (int i = 0; i < 8; ++i) {
            int c = i * 4 + cg;
            const float* wr = &swo[c * 32];
            float acc = sbo[c] + xr[c];
#pragma unroll
            for (int k = 0; k < 32; ++k) acc += orow[k] * wr[k];
            sqkv[r * 100 + c] = acc;
        }
    }
    __syncthreads();

    if (tid < 64) {
        float mu = 0.f;
#pragma unroll
        for (int c = 0; c < 32; ++c) mu += sqkv[tid * 100 + c];
        mu *= (1.f / 32.f);
        float var = 0.f;
#pragma unroll
        for (int c = 0; c < 32; ++c) { float d = sqkv[tid * 100 + c] - mu; var += d * d; }
        var *= (1.f / 32.f);
        smean2[tid] = mu;
        srstd2[tid] = rsqrtf(var + LN_EPS);
    }
    __syncthreads();

    for (int pass = 0; pass < 2; ++pass) {
        int idx = pass * 256 + tid;      // 512 = 16 lo x 32 c
        int loo = idx >> 5, c = idx & 31;
        float acc = 0.f;
#pragma unroll
        for (int ss = 0; ss < 4; ++ss) {
            int rr = loo * 4 + ss;
            acc += (sqkv[rr * 100 + c] - smean2[rr]) * srstd2[rr];
        }
        float mval = 0.25f * acc * sg[c] + sb[c];
        m_out[(b * 64 + l0 + loo) * 32 + c] = mval;
        smv[loo][c] = mval * mval;
    }
    __syncthreads();

    if (tid < 16) {
        float sum = 0.f;
#pragma unroll
        for (int c = 0; c < 32; ++c) sum += smv[tid][c];
        nrm_out[b * 64 + l0 + tid] = sqrtf(sum);
    }
}

// ---------------------------------------------------------------------------
// Kernel 3: factorized outer-product + proj + LN + SiLU + transpose
// feat[b,i,j,cp] = (T_i[cp]·m_j)/(|m_i||m_j|) + pb;  T_i = pw·m_i
// one block per (b, 16-i chunk): 256 blocks x 256 threads
// T phase: m_i tile distributed in wave regs, fetched via __shfl (VALU pipe);
//          each thread owns 2 weight rows -> 64 conflict-free LDS reads.
// out phase: sT rows read as float4 broadcast (16B-aligned, stride 520).
// ---------------------------------------------------------------------------
__global__ __launch_bounds__(256) void k_pair(
    const float* __restrict__ m, const float* __restrict__ nrm,
    const float* __restrict__ pw, const float* __restrict__ pb,
    const float* __restrict__ pg, const float* __restrict__ pbeta,
    float* __restrict__ out)
{
    __shared__ float spw[512 * 33];     // [rem = cp*32+d][c], pad 33 -> 2-way free
    __shared__ float sT[16 * 520];      // [il][rem], stride 520 (16B-aligned)
    __shared__ float smj[64][33];
    __shared__ float snj[64];
    __shared__ float sbias[16], sgam[16], sbet[16];

    const int bx = blockIdx.x;          // 64 b x 4 i-chunks
    const int b  = bx >> 2;
    const int i0 = (bx & 3) * 16;
    const int tid = threadIdx.x;

    const float* mb = m + b * 2048;
    for (int n = tid; n < 2048; n += 256) smj[n >> 5][n & 31] = mb[n];
    if (tid < 64) snj[tid] = nrm[b * 64 + tid];
    if (tid < 16) {
        sbias[tid] = pb[tid];
        sgam[tid]  = pg[tid];
        sbet[tid]  = pbeta[tid];
    }
    // transpose-stage pw with float4 global reads; LDS write banks (d+c)%32 -> free
    for (int t = 0; t < 16; ++t) {
        int n4 = (t * 256 + tid) * 4;          // 16384 floats total
        float4 wv = *(const float4*)&pw[n4];
        int cp = n4 >> 10, c = (n4 >> 5) & 31, d = n4 & 31;
        float* dst = &spw[(cp * 32 + d) * 33 + c];
        dst[0]      = wv.x;
        dst[33]     = wv.y;   // d+1
        dst[66]     = wv.z;   // d+2
        dst[99]     = wv.w;   // d+3
    }
    __syncthreads();

    // distribute m_i tile into wave registers: lane = il*4 + quarter
    const int lane = tid & 63;
    float mi8[8];
    {
        const int mil = lane >> 2, mq = lane & 3;
#pragma unroll
        for (int k = 0; k < 8; ++k) mi8[k] = smj[i0 + mil][mq * 8 + k];
    }

    // T phase: thread owns rem0 = tid, rem1 = tid + 256
    {
        float acc0[16], acc1[16];
#pragma unroll
        for (int il = 0; il < 16; ++il) { acc0[il] = 0.f; acc1[il] = 0.f; }
        const float* w0p = &spw[tid * 33];
        const float* w1p = &spw[(tid + 256) * 33];
#pragma unroll
        for (int c = 0; c < 32; ++c) {
            float w0 = w0p[c];
            float w1 = w1p[c];
            const int src = c >> 3, k = c & 7;
#pragma unroll
            for (int il = 0; il < 16; ++il) {
                float mval = __shfl(mi8[k], il * 4 + src, 64);
                acc0[il] += mval * w0;
                acc1[il] += mval * w1;
            }
        }
#pragma unroll
        for (int il = 0; il < 16; ++il) {
            sT[il * 520 + tid]       = acc0[il];
            sT[il * 520 + tid + 256] = acc1[il];
        }
    }
    __syncthreads();

    // out phase: thread (ih = tid>>6, j = tid&63); 4 i's per thread
    const int j  = tid & 63;
    const int ih = tid >> 6;
    float mj[32];
#pragma unroll
    for (int d = 0; d < 32; ++d) mj[d] = smj[j][d];
    const float nj = snj[j];

    for (int q = 0; q < 4; ++q) {
        const int il = ih * 4 + q;
        const int ig = i0 + il;
        const float invn = 1.f / fmaxf(snj[ig] * nj, 1e-6f);
        float f[16];
#pragma unroll
        for (int cp = 0; cp < 16; ++cp) {
            const float4* tr = (const float4*)&sT[il * 520 + cp * 32]; // b128 broadcast
            float acc = 0.f;
#pragma unroll
            for (int d4 = 0; d4 < 8; ++d4) {
                float4 tv = tr[d4];
                acc += tv.x * mj[d4 * 4 + 0];
                acc += tv.y * mj[d4 * 4 + 1];
                acc += tv.z * mj[d4 * 4 + 2];
                acc += tv.w * mj[d4 * 4 + 3];
            }
            f[cp] = acc * invn + sbias[cp];
        }
        float mu = 0.f;
#pragma unroll
        for (int cp = 0; cp < 16; ++cp) mu += f[cp];
        mu *= (1.f / 16.f);
        float var = 0.f;
#pragma unroll
        for (int cp = 0; cp < 16; ++cp) { float d = f[cp] - mu; var += d * d; }
        var *= (1.f / 16.f);
        const float rstd = rsqrtf(var + LN_EPS);
#pragma unroll
        for (int cp = 0; cp < 16; ++cp) {
            float v = (f[cp] - mu) * rstd * sgam[cp] + sbet[cp];
            float sl = v / (1.f + __expf(-v));
            out[((b * 16 + cp) * 64 + ig) * 64 + j] = sl;
        }
    }
}

// ---------------------------------------------------------------------------
extern "C" void kernel_launch(void* const* d_in, const int* in_sizes, int n_in,
                              void* d_out, int out_size, void* d_ws, size_t ws_size,
                              hipStream_t stream) {
    const float* ctcf  = (const float*)d_in[0];
    const float* hac   = (const float*)d_in[1];
    const float* me1   = (const float*)d_in[2];
    const float* me3   = (const float*)d_in[3];
    const float* ew    = (const float*)d_in[4];
    const float* ebias = (const float*)d_in[5];
    const float* pe    = (const float*)d_in[6];
    const float* riw   = (const float*)d_in[7];
    const float* rib   = (const float*)d_in[8];
    const float* row_  = (const float*)d_in[9];
    const float* rob   = (const float*)d_in[10];
    const float* rlg   = (const float*)d_in[11];
    const float* rlb   = (const float*)d_in[12];
    const float* ciw   = (const float*)d_in[13];
    const float* cib   = (const float*)d_in[14];
    const float* cow   = (const float*)d_in[15];
    const float* cob   = (const float*)d_in[16];
    const float* clg   = (const float*)d_in[17];
    const float* clb   = (const float*)d_in[18];
    const float* pw    = (const float*)d_in[19];
    const float* pb    = (const float*)d_in[20];
    const float* pg    = (const float*)d_in[21];
    const float* pbt   = (const float*)d_in[22];

    float* out = (float*)d_out;

    // msaR (2 MB) borrows d_out (16 MB f32): fully consumed by k_col before
    // k_pair writes out (serial stream). m + norms in ws (~528 KB).
    float* msaR = (float*)d_out;
    float* mbuf = (float*)d_ws;                  // 64*64*32 floats
    float* nbuf = mbuf + 64 * 64 * 32;           // 64*64 floats

    k_row<<<256, 256, 0, stream>>>(ctcf, hac, me1, me3, ew, ebias, pe,
                                   riw, rib, row_, rob, rlg, rlb, msaR);
    k_col<<<256, 256, 0, stream>>>(msaR, ciw, cib, cow, cob, clg, clb,
                                   mbuf, nbuf);
    k_pair<<<256, 256, 0, stream>>>(mbuf, nbuf, pw, pb, pg, pbt, out);
}

// Round 6
// 164.692 us; speedup vs baseline: 1.0193x; 1.0193x over previous
//
#include <hip/hip_runtime.h>
#include <hip/hip_bf16.h>

#define LN_EPS 1e-5f

__device__ __forceinline__ float dot8(float4 a0, float4 a1, float4 b0, float4 b1) {
    return a0.x * b0.x + a0.y * b0.y + a0.z * b0.z + a0.w * b0.w +
           a1.x * b1.x + a1.y * b1.y + a1.z * b1.z + a1.w * b1.w;
}

// ---------------------------------------------------------------------------
// Kernel 1: embed + pos + row attention (64 bins) + residual + LN
// one block per (b, s): 256 blocks x 256 threads
// All wave-uniform LDS reads are float4 (ds_read_b128 broadcast).
// ---------------------------------------------------------------------------
__global__ __launch_bounds__(256) void k_row(
    const float* __restrict__ ctcf, const float* __restrict__ hac,
    const float* __restrict__ me1,  const float* __restrict__ me3,
    const float* __restrict__ ew,   const float* __restrict__ eb,
    const float* __restrict__ pe,
    const float* __restrict__ w_in, const float* __restrict__ b_in,
    const float* __restrict__ w_out,const float* __restrict__ b_out,
    const float* __restrict__ ln_g, const float* __restrict__ ln_b,
    float* __restrict__ msaR)
{
    __shared__ float sx[64][33];        // x tile (residual source)
    __shared__ float sqkv[64 * 100];    // qkv rows, stride 100 (16B-aligned)
    __shared__ float so[64][33];        // attention output
    __shared__ float swin[96 * 32];     // rows 128B-aligned -> b128 broadcast
    __shared__ float swout[32 * 32];
    __shared__ float sbin[96];
    __shared__ float sbout[32], sg[32], sb[32];
    __shared__ float smean[64], srstd[64];

    const int blk = blockIdx.x;          // b*4 + s
    const int s   = blk & 3;
    const int b   = blk >> 2;
    const int tid = threadIdx.x;

    const float* chip = (s == 0) ? ctcf : (s == 1) ? hac : (s == 2) ? me1 : me3;

    for (int n = tid; n < 96 * 32; n += 256) swin[n] = w_in[n];
    for (int n = tid; n < 32 * 32; n += 256) swout[n] = w_out[n];
    if (tid < 96) sbin[tid] = b_in[tid];
    if (tid < 32) {
        sbout[tid] = b_out[tid];
        sg[tid] = ln_g[tid];
        sb[tid] = ln_b[tid];
    }
    for (int n = tid; n < 2048; n += 256) {
        int l = n >> 5, c = n & 31;
        sx[l][c] = chip[b * 64 + l] * ew[c] + eb[c] + pe[l * 32 + c];
    }
    __syncthreads();

    const int l  = tid & 63;
    const int cg = tid >> 6;             // wave id -> wave-uniform

    float xr[32];
#pragma unroll
    for (int c = 0; c < 32; ++c) xr[c] = sx[l][c];

    // qkv[l][cc] = x[l]·w_in[cc] + b_in[cc]; w row via b128 broadcast
#pragma unroll
    for (int i = 0; i < 24; ++i) {
        int cc = i * 4 + cg;
        const float4* wr4 = (const float4*)&swin[cc * 32];
        float acc = sbin[cc];
#pragma unroll
        for (int c4 = 0; c4 < 8; ++c4) {
            float4 wv = wr4[c4];
            acc += xr[c4 * 4 + 0] * wv.x + xr[c4 * 4 + 1] * wv.y +
                   xr[c4 * 4 + 2] * wv.z + xr[c4 * 4 + 3] * wv.w;
        }
        sqkv[l * 100 + cc] = acc;
    }
    __syncthreads();

    // attention: thread (h = cg, l); online softmax; K/V rows b128 broadcast
    {
        const int h = cg;
        const float4* qp = (const float4*)&sqkv[l * 100 + h * 8];
        float4 q0 = qp[0], q1 = qp[1];
        const float scale = 0.35355339059327373f;  // 1/sqrt(8)
        float mrun = -1e30f, denom = 0.f, a[8];
#pragma unroll
        for (int dd = 0; dd < 8; ++dd) a[dd] = 0.f;
        for (int j = 0; j < 64; ++j) {
            const float4* kp = (const float4*)&sqkv[j * 100 + 32 + h * 8];
            float4 k0 = kp[0], k1 = kp[1];
            float sc = dot8(q0, q1, k0, k1) * scale;
            const float4* vp = (const float4*)&sqkv[j * 100 + 64 + h * 8];
            float4 v0 = vp[0], v1 = vp[1];
            float mnew = fmaxf(mrun, sc);
            float corr = __expf(mrun - mnew);
            float w = __expf(sc - mnew);
            denom = denom * corr + w;
            a[0] = a[0] * corr + w * v0.x;  a[1] = a[1] * corr + w * v0.y;
            a[2] = a[2] * corr + w * v0.z;  a[3] = a[3] * corr + w * v0.w;
            a[4] = a[4] * corr + w * v1.x;  a[5] = a[5] * corr + w * v1.y;
            a[6] = a[6] * corr + w * v1.z;  a[7] = a[7] * corr + w * v1.w;
            mrun = mnew;
        }
        float inv = 1.f / denom;
#pragma unroll
        for (int dd = 0; dd < 8; ++dd) so[l][h * 8 + dd] = a[dd] * inv;
    }
    __syncthreads();

    // out proj + residual -> sqkv cols 0..31 (w row b128 broadcast)
    {
        float orow[32];
#pragma unroll
        for (int k = 0; k < 32; ++k) orow[k] = so[l][k];
#pragma unroll
        for (int i = 0; i < 8; ++i) {
            int c = i * 4 + cg;
            const float4* wr4 = (const float4*)&swout[c * 32];
            float acc = sbout[c] + xr[c];
#pragma unroll
            for (int k4 = 0; k4 < 8; ++k4) {
                float4 wv = wr4[k4];
                acc += orow[k4 * 4 + 0] * wv.x + orow[k4 * 4 + 1] * wv.y +
                       orow[k4 * 4 + 2] * wv.z + orow[k4 * 4 + 3] * wv.w;
            }
            sqkv[l * 100 + c] = acc;
        }
    }
    __syncthreads();

    if (tid < 64) {
        float mu = 0.f;
#pragma unroll
        for (int c = 0; c < 32; ++c) mu += sqkv[tid * 100 + c];
        mu *= (1.f / 32.f);
        float var = 0.f;
#pragma unroll
        for (int c = 0; c < 32; ++c) { float d = sqkv[tid * 100 + c] - mu; var += d * d; }
        var *= (1.f / 32.f);
        smean[tid] = mu;
        srstd[tid] = rsqrtf(var + LN_EPS);
    }
    __syncthreads();

    float* outp = msaR + blk * 2048;     // (B,S,Lb,C)
    for (int n = tid; n < 2048; n += 256) {
        int ll = n >> 5, c = n & 31;
        outp[n] = (sqkv[ll * 100 + c] - smean[ll]) * srstd[ll] * sg[c] + sb[c];
    }
}

// ---------------------------------------------------------------------------
// Kernel 2: column attention (4 tracks) + residual + LN + track mean + norm
// one block per (b, 16-bin chunk): 256 blocks x 256 threads
// ---------------------------------------------------------------------------
__global__ __launch_bounds__(256) void k_col(
    const float* __restrict__ msaR,
    const float* __restrict__ w_in, const float* __restrict__ b_in,
    const float* __restrict__ w_out,const float* __restrict__ b_out,
    const float* __restrict__ ln_g, const float* __restrict__ ln_b,
    float* __restrict__ m_out, float* __restrict__ nrm_out)
{
    __shared__ float sx[64][33];        // rows keyed s*16+lo
    __shared__ float sqkv[64 * 100];    // rows keyed r = lo*4+s
    __shared__ float so[64][33];        // rows keyed r
    __shared__ float swi[96 * 32];
    __shared__ float swo[32 * 32];
    __shared__ float sbi[96];
    __shared__ float sbo[32], sg[32], sb[32];
    __shared__ float smean2[64], srstd2[64];
    __shared__ float smv[16][33];

    const int bx = blockIdx.x;           // 64 b x 4 chunks
    const int b  = bx >> 2;
    const int l0 = (bx & 3) * 16;
    const int tid = threadIdx.x;

    for (int n = tid; n < 96 * 32; n += 256) swi[n] = w_in[n];
    for (int n = tid; n < 32 * 32; n += 256) swo[n] = w_out[n];
    if (tid < 96) sbi[tid] = b_in[tid];
    if (tid < 32) {
        sbo[tid] = b_out[tid];
        sg[tid] = ln_g[tid];
        sb[tid] = ln_b[tid];
    }
    for (int n = tid; n < 2048; n += 256) {
        int s = n >> 9, lo = (n >> 5) & 15, c = n & 31;
        sx[s * 16 + lo][c] = msaR[((b * 4 + s) * 64 + l0 + lo) * 32 + c];
    }
    __syncthreads();

    const int r  = tid & 63;
    const int sS = r & 3, lo = r >> 2;
    const int cg = tid >> 6;

    float xr[32];
#pragma unroll
    for (int c = 0; c < 32; ++c) xr[c] = sx[sS * 16 + lo][c];

#pragma unroll
    for (int i = 0; i < 24; ++i) {
        int cc = i * 4 + cg;
        const float4* wr4 = (const float4*)&swi[cc * 32];
        float acc = sbi[cc];
#pragma unroll
        for (int c4 = 0; c4 < 8; ++c4) {
            float4 wv = wr4[c4];
            acc += xr[c4 * 4 + 0] * wv.x + xr[c4 * 4 + 1] * wv.y +
                   xr[c4 * 4 + 2] * wv.z + xr[c4 * 4 + 3] * wv.w;
        }
        sqkv[r * 100 + cc] = acc;
    }
    __syncthreads();

    // attention over 4 tracks: thread (la = tid>>4, h = (tid>>2)&3, ia = tid&3)
    {
        const int la = tid >> 4, h = (tid >> 2) & 3, ia = tid & 3;
        const float scale = 0.35355339059327373f;
        const float4* qp = (const float4*)&sqkv[(la * 4 + ia) * 100 + h * 8];
        float4 q0 = qp[0], q1 = qp[1];
        float sc[4];
        float mx = -1e30f;
#pragma unroll
        for (int jj = 0; jj < 4; ++jj) {
            const float4* kp = (const float4*)&sqkv[(la * 4 + jj) * 100 + 32 + h * 8];
            sc[jj] = dot8(q0, q1, kp[0], kp[1]) * scale;
            mx = fmaxf(mx, sc[jj]);
        }
        float den = 0.f;
#pragma unroll
        for (int jj = 0; jj < 4; ++jj) { sc[jj] = __expf(sc[jj] - mx); den += sc[jj]; }
        float inv = 1.f / den;
        float a[8];
#pragma unroll
        for (int dd = 0; dd < 8; ++dd) a[dd] = 0.f;
#pragma unroll
        for (int jj = 0; jj < 4; ++jj) {
            const float4* vp = (const float4*)&sqkv[(la * 4 + jj) * 100 + 64 + h * 8];
            float4 v0 = vp[0], v1 = vp[1];
            float wgt = sc[jj];
            a[0] += wgt * v0.x;  a[1] += wgt * v0.y;
            a[2] += wgt * v0.z;  a[3] += wgt * v0.w;
            a[4] += wgt * v1.x;  a[5] += wgt * v1.y;
            a[6] += wgt * v1.z;  a[7] += wgt * v1.w;
        }
#pragma unroll
        for (int dd = 0; dd < 8; ++dd) so[la * 4 + ia][h * 8 + dd] = a[dd] * inv;
    }
    __syncthreads();

    {
        float orow[32];
#pragma unroll
        for (int k = 0; k < 32; ++k) orow[k] = so[r][k];
#pragma unroll
        for (int i = 0; i < 8; ++i) {
            int c = i * 4 + cg;
            const float4* wr4 = (const float4*)&swo[c * 32];
            float acc = sbo[c] + xr[c];
#pragma unroll
            for (int k4 = 0; k4 < 8; ++k4) {
                float4 wv = wr4[k4];
                acc += orow[k4 * 4 + 0] * wv.x + orow[k4 * 4 + 1] * wv.y +
                       orow[k4 * 4 + 2] * wv.z + orow[k4 * 4 + 3] * wv.w;
            }
            sqkv[r * 100 + c] = acc;
        }
    }
    __syncthreads();

    if (tid < 64) {
        float mu = 0.f;
#pragma unroll
        for (int c = 0; c < 32; ++c) mu += sqkv[tid * 100 + c];
        mu *= (1.f / 32.f);
        float var = 0.f;
#pragma unroll
        for (int c = 0; c < 32; ++c) { float d = sqkv[tid * 100 + c] - mu; var += d * d; }
        var *= (1.f / 32.f);
        smean2[tid] = mu;
        srstd2[tid] = rsqrtf(var + LN_EPS);
    }
    __syncthreads();

    for (int pass = 0; pass < 2; ++pass) {
        int idx = pass * 256 + tid;      // 512 = 16 lo x 32 c
        int loo = idx >> 5, c = idx & 31;
        float acc = 0.f;
#pragma unroll
        for (int ss = 0; ss < 4; ++ss) {
            int rr = loo * 4 + ss;
            acc += (sqkv[rr * 100 + c] - smean2[rr]) * srstd2[rr];
        }
        float mval = 0.25f * acc * sg[c] + sb[c];
        m_out[(b * 64 + l0 + loo) * 32 + c] = mval;
        smv[loo][c] = mval * mval;
    }
    __syncthreads();

    if (tid < 16) {
        float sum = 0.f;
#pragma unroll
        for (int c = 0; c < 32; ++c) sum += smv[tid][c];
        nrm_out[b * 64 + l0 + tid] = sqrtf(sum);
    }
}

// ---------------------------------------------------------------------------
// Kernel 3: factorized outer-product + proj + LN + SiLU + transpose
// feat[b,i,j,cp] = (T_i[cp]·m_j)/(|m_i||m_j|) + pb;  T_i = pw·m_i
// 256 blocks (b x 4 i-chunks) x 256 threads.
// T phase is WAVE-LOCAL: wave w computes rows il=4w..4w+3; lane owns
// rem = lane + 64k, reading pw directly from global (L2-hot, coalesced).
// No barrier between T and out (same-wave ds ordering via lgkmcnt).
// ---------------------------------------------------------------------------
__global__ __launch_bounds__(256) void k_pair(
    const float* __restrict__ m, const float* __restrict__ nrm,
    const float* __restrict__ pw, const float* __restrict__ pb,
    const float* __restrict__ pg, const float* __restrict__ pbeta,
    float* __restrict__ out)
{
    __shared__ float smj[64][36];       // stride 36 -> rows 16B-aligned
    __shared__ float sT[16 * 520];      // [il][rem], stride 520 (16B-aligned)
    __shared__ float snj[64];
    __shared__ float sbias[16], sgam[16], sbet[16];

    const int bx = blockIdx.x;          // 64 b x 4 i-chunks
    const int b  = bx >> 2;
    const int i0 = (bx & 3) * 16;
    const int tid = threadIdx.x;
    const int lane = tid & 63, w = tid >> 6;

    const float* mb = m + b * 2048;
    for (int n = tid; n < 2048; n += 256) smj[n >> 5][n & 31] = mb[n];
    if (tid < 64) snj[tid] = nrm[b * 64 + tid];
    if (tid < 16) {
        sbias[tid] = pb[tid];
        sgam[tid]  = pg[tid];
        sbet[tid]  = pbeta[tid];
    }
    __syncthreads();

    // T phase: treg[q][k] = T[i0+4w+q][lane + 64k]
    //   = sum_c m[i0+4w+q][c] * pw[( (lane>>5) + 2k )*1024 + c*32 + (lane&31)]
    float treg[4][8];
#pragma unroll
    for (int q = 0; q < 4; ++q)
#pragma unroll
        for (int k = 0; k < 8; ++k) treg[q][k] = 0.f;
    {
        const float* pwl = pw + (lane >> 5) * 1024 + (lane & 31);
#pragma unroll 4
        for (int c = 0; c < 32; ++c) {
            float m0 = smj[i0 + w * 4 + 0][c];
            float m1 = smj[i0 + w * 4 + 1][c];
            float m2 = smj[i0 + w * 4 + 2][c];
            float m3 = smj[i0 + w * 4 + 3][c];
#pragma unroll
            for (int k = 0; k < 8; ++k) {
                float wv = pwl[k * 2048 + c * 32];   // coalesced, L2-hot
                treg[0][k] += m0 * wv;
                treg[1][k] += m1 * wv;
                treg[2][k] += m2 * wv;
                treg[3][k] += m3 * wv;
            }
        }
    }
#pragma unroll
    for (int q = 0; q < 4; ++q)
#pragma unroll
        for (int k = 0; k < 8; ++k)
            sT[(w * 4 + q) * 520 + lane + 64 * k] = treg[q][k];
    // wave-local write->read: compiler-ordered via lgkmcnt, no __syncthreads

    // out phase: lane = j; wave w handles il = 4w..4w+3
    const int j = lane;
    float mj[32];
    {
        const float4* mjp = (const float4*)&smj[j][0];
#pragma unroll
        for (int d4 = 0; d4 < 8; ++d4) {
            float4 t = mjp[d4];
            mj[d4 * 4 + 0] = t.x;  mj[d4 * 4 + 1] = t.y;
            mj[d4 * 4 + 2] = t.z;  mj[d4 * 4 + 3] = t.w;
        }
    }
    const float nj = snj[j];

    for (int q = 0; q < 4; ++q) {
        const int il = w * 4 + q;
        const int ig = i0 + il;
        const float invn = 1.f / fmaxf(snj[ig] * nj, 1e-6f);
        float f[16];
#pragma unroll
        for (int cp = 0; cp < 16; ++cp) {
            const float4* tr = (const float4*)&sT[il * 520 + cp * 32]; // b128 bcast
            float acc = 0.f;
#pragma unroll
            for (int d4 = 0; d4 < 8; ++d4) {
                float4 tv = tr[d4];
                acc += tv.x * mj[d4 * 4 + 0] + tv.y * mj[d4 * 4 + 1] +
                       tv.z * mj[d4 * 4 + 2] + tv.w * mj[d4 * 4 + 3];
            }
            f[cp] = acc * invn + sbias[cp];
        }
        float mu = 0.f;
#pragma unroll
        for (int cp = 0; cp < 16; ++cp) mu += f[cp];
        mu *= (1.f / 16.f);
        float var = 0.f;
#pragma unroll
        for (int cp = 0; cp < 16; ++cp) { float d = f[cp] - mu; var += d * d; }
        var *= (1.f / 16.f);
        const float rstd = rsqrtf(var + LN_EPS);
#pragma unroll
        for (int cp = 0; cp < 16; ++cp) {
            float v = (f[cp] - mu) * rstd * sgam[cp] + sbet[cp];
            float sl = v / (1.f + __expf(-v));
            out[((b * 16 + cp) * 64 + ig) * 64 + j] = sl;
        }
    }
}

// ---------------------------------------------------------------------------
extern "C" void kernel_launch(void* const* d_in, const int* in_sizes, int n_in,
                              void* d_out, int out_size, void* d_ws, size_t ws_size,
                              hipStream_t stream) {
    const float* ctcf  = (const float*)d_in[0];
    const float* hac   = (const float*)d_in[1];
    const float* me1   = (const float*)d_in[2];
    const float* me3   = (const float*)d_in[3];
    const float* ew    = (const float*)d_in[4];
    const float* ebias = (const float*)d_in[5];
    const float* pe    = (const float*)d_in[6];
    const float* riw   = (const float*)d_in[7];
    const float* rib   = (const float*)d_in[8];
    const float* row_  = (const float*)d_in[9];
    const float* rob   = (const float*)d_in[10];
    const float* rlg   = (const float*)d_in[11];
    const float* rlb   = (const float*)d_in[12];
    const float* ciw   = (const float*)d_in[13];
    const float* cib   = (const float*)d_in[14];
    const float* cow   = (const float*)d_in[15];
    const float* cob   = (const float*)d_in[16];
    const float* clg   = (const float*)d_in[17];
    const float* clb   = (const float*)d_in[18];
    const float* pw    = (const float*)d_in[19];
    const float* pb    = (const float*)d_in[20];
    const float* pg    = (const float*)d_in[21];
    const float* pbt   = (const float*)d_in[22];

    float* out = (float*)d_out;

    // msaR (2 MB) borrows d_out (16 MB f32): fully consumed by k_col before
    // k_pair writes out (serial stream). m + norms in ws (~528 KB).
    float* msaR = (float*)d_out;
    float* mbuf = (float*)d_ws;                  // 64*64*32 floats
    float* nbuf = mbuf + 64 * 64 * 32;           // 64*64 floats

    k_row<<<256, 256, 0, stream>>>(ctcf, hac, me1, me3, ew, ebias, pe,
                                   riw, rib, row_, rob, rlg, rlb, msaR);
    k_col<<<256, 256, 0, stream>>>(msaR, ciw, cib, cow, cob, clg, clb,
                                   mbuf, nbuf);
    k_pair<<<256, 256, 0, stream>>>(mbuf, nbuf, pw, pb, pg, pbt, out);
}

// Round 7
// 156.987 us; speedup vs baseline: 1.0693x; 1.0491x over previous
//
#include <hip/hip_runtime.h>
#include <hip/hip_bf16.h>

#define LN_EPS 1e-5f

__device__ __forceinline__ float dot8(float4 a0, float4 a1, float4 b0, float4 b1) {
    return a0.x * b0.x + a0.y * b0.y + a0.z * b0.z + a0.w * b0.w +
           a1.x * b1.x + a1.y * b1.y + a1.z * b1.z + a1.w * b1.w;
}

// ---------------------------------------------------------------------------
// Kernel 1: embed + pos + row attention (64 bins) + residual + LN
// one block per (b, s): 256 blocks x 256 threads
// All wave-uniform LDS reads are float4 (ds_read_b128 broadcast).
// ---------------------------------------------------------------------------
__global__ __launch_bounds__(256) void k_row(
    const float* __restrict__ ctcf, const float* __restrict__ hac,
    const float* __restrict__ me1,  const float* __restrict__ me3,
    const float* __restrict__ ew,   const float* __restrict__ eb,
    const float* __restrict__ pe,
    const float* __restrict__ w_in, const float* __restrict__ b_in,
    const float* __restrict__ w_out,const float* __restrict__ b_out,
    const float* __restrict__ ln_g, const float* __restrict__ ln_b,
    float* __restrict__ msaR)
{
    __shared__ float sx[64][33];        // x tile (residual source)
    __shared__ float sqkv[64 * 100];    // qkv rows, stride 100 (16B-aligned)
    __shared__ float so[64][33];        // attention output
    __shared__ float swin[96 * 32];     // rows 128B-aligned -> b128 broadcast
    __shared__ float swout[32 * 32];
    __shared__ float sbin[96];
    __shared__ float sbout[32], sg[32], sb[32];
    __shared__ float smean[64], srstd[64];

    const int blk = blockIdx.x;          // b*4 + s
    const int s   = blk & 3;
    const int b   = blk >> 2;
    const int tid = threadIdx.x;

    const float* chip = (s == 0) ? ctcf : (s == 1) ? hac : (s == 2) ? me1 : me3;

    for (int n = tid; n < 96 * 32; n += 256) swin[n] = w_in[n];
    for (int n = tid; n < 32 * 32; n += 256) swout[n] = w_out[n];
    if (tid < 96) sbin[tid] = b_in[tid];
    if (tid < 32) {
        sbout[tid] = b_out[tid];
        sg[tid] = ln_g[tid];
        sb[tid] = ln_b[tid];
    }
    for (int n = tid; n < 2048; n += 256) {
        int l = n >> 5, c = n & 31;
        sx[l][c] = chip[b * 64 + l] * ew[c] + eb[c] + pe[l * 32 + c];
    }
    __syncthreads();

    const int l  = tid & 63;
    const int cg = tid >> 6;             // wave id -> wave-uniform

    float xr[32];
#pragma unroll
    for (int c = 0; c < 32; ++c) xr[c] = sx[l][c];

    // qkv[l][cc] = x[l]·w_in[cc] + b_in[cc]; w row via b128 broadcast
#pragma unroll
    for (int i = 0; i < 24; ++i) {
        int cc = i * 4 + cg;
        const float4* wr4 = (const float4*)&swin[cc * 32];
        float acc = sbin[cc];
#pragma unroll
        for (int c4 = 0; c4 < 8; ++c4) {
            float4 wv = wr4[c4];
            acc += xr[c4 * 4 + 0] * wv.x + xr[c4 * 4 + 1] * wv.y +
                   xr[c4 * 4 + 2] * wv.z + xr[c4 * 4 + 3] * wv.w;
        }
        sqkv[l * 100 + cc] = acc;
    }
    __syncthreads();

    // attention: thread (h = cg, l); online softmax; K/V rows b128 broadcast
    {
        const int h = cg;
        const float4* qp = (const float4*)&sqkv[l * 100 + h * 8];
        float4 q0 = qp[0], q1 = qp[1];
        const float scale = 0.35355339059327373f;  // 1/sqrt(8)
        float mrun = -1e30f, denom = 0.f, a[8];
#pragma unroll
        for (int dd = 0; dd < 8; ++dd) a[dd] = 0.f;
        for (int j = 0; j < 64; ++j) {
            const float4* kp = (const float4*)&sqkv[j * 100 + 32 + h * 8];
            float4 k0 = kp[0], k1 = kp[1];
            float sc = dot8(q0, q1, k0, k1) * scale;
            const float4* vp = (const float4*)&sqkv[j * 100 + 64 + h * 8];
            float4 v0 = vp[0], v1 = vp[1];
            float mnew = fmaxf(mrun, sc);
            float corr = __expf(mrun - mnew);
            float w = __expf(sc - mnew);
            denom = denom * corr + w;
            a[0] = a[0] * corr + w * v0.x;  a[1] = a[1] * corr + w * v0.y;
            a[2] = a[2] * corr + w * v0.z;  a[3] = a[3] * corr + w * v0.w;
            a[4] = a[4] * corr + w * v1.x;  a[5] = a[5] * corr + w * v1.y;
            a[6] = a[6] * corr + w * v1.z;  a[7] = a[7] * corr + w * v1.w;
            mrun = mnew;
        }
        float inv = 1.f / denom;
#pragma unroll
        for (int dd = 0; dd < 8; ++dd) so[l][h * 8 + dd] = a[dd] * inv;
    }
    __syncthreads();

    // out proj + residual -> sqkv cols 0..31 (w row b128 broadcast)
    {
        float orow[32];
#pragma unroll
        for (int k = 0; k < 32; ++k) orow[k] = so[l][k];
#pragma unroll
        for (int i = 0; i < 8; ++i) {
            int c = i * 4 + cg;
            const float4* wr4 = (const float4*)&swout[c * 32];
            float acc = sbout[c] + xr[c];
#pragma unroll
            for (int k4 = 0; k4 < 8; ++k4) {
                float4 wv = wr4[k4];
                acc += orow[k4 * 4 + 0] * wv.x + orow[k4 * 4 + 1] * wv.y +
                       orow[k4 * 4 + 2] * wv.z + orow[k4 * 4 + 3] * wv.w;
            }
            sqkv[l * 100 + c] = acc;
        }
    }
    __syncthreads();

    if (tid < 64) {
        float mu = 0.f;
#pragma unroll
        for (int c = 0; c < 32; ++c) mu += sqkv[tid * 100 + c];
        mu *= (1.f / 32.f);
        float var = 0.f;
#pragma unroll
        for (int c = 0; c < 32; ++c) { float d = sqkv[tid * 100 + c] - mu; var += d * d; }
        var *= (1.f / 32.f);
        smean[tid] = mu;
        srstd[tid] = rsqrtf(var + LN_EPS);
    }
    __syncthreads();

    float* outp = msaR + blk * 2048;     // (B,S,Lb,C)
    for (int n = tid; n < 2048; n += 256) {
        int ll = n >> 5, c = n & 31;
        outp[n] = (sqkv[ll * 100 + c] - smean[ll]) * srstd[ll] * sg[c] + sb[c];
    }
}

// ---------------------------------------------------------------------------
// Kernel 2: column attention (4 tracks) + residual + LN + track mean + norm
// one block per (b, 16-bin chunk): 256 blocks x 256 threads
// ---------------------------------------------------------------------------
__global__ __launch_bounds__(256) void k_col(
    const float* __restrict__ msaR,
    const float* __restrict__ w_in, const float* __restrict__ b_in,
    const float* __restrict__ w_out,const float* __restrict__ b_out,
    const float* __restrict__ ln_g, const float* __restrict__ ln_b,
    float* __restrict__ m_out, float* __restrict__ nrm_out)
{
    __shared__ float sx[64][33];        // rows keyed s*16+lo
    __shared__ float sqkv[64 * 100];    // rows keyed r = lo*4+s
    __shared__ float so[64][33];        // rows keyed r
    __shared__ float swi[96 * 32];
    __shared__ float swo[32 * 32];
    __shared__ float sbi[96];
    __shared__ float sbo[32], sg[32], sb[32];
    __shared__ float smean2[64], srstd2[64];
    __shared__ float smv[16][33];

    const int bx = blockIdx.x;           // 64 b x 4 chunks
    const int b  = bx >> 2;
    const int l0 = (bx & 3) * 16;
    const int tid = threadIdx.x;

    for (int n = tid; n < 96 * 32; n += 256) swi[n] = w_in[n];
    for (int n = tid; n < 32 * 32; n += 256) swo[n] = w_out[n];
    if (tid < 96) sbi[tid] = b_in[tid];
    if (tid < 32) {
        sbo[tid] = b_out[tid];
        sg[tid] = ln_g[tid];
        sb[tid] = ln_b[tid];
    }
    for (int n = tid; n < 2048; n += 256) {
        int s = n >> 9, lo = (n >> 5) & 15, c = n & 31;
        sx[s * 16 + lo][c] = msaR[((b * 4 + s) * 64 + l0 + lo) * 32 + c];
    }
    __syncthreads();

    const int r  = tid & 63;
    const int sS = r & 3, lo = r >> 2;
    const int cg = tid >> 6;

    float xr[32];
#pragma unroll
    for (int c = 0; c < 32; ++c) xr[c] = sx[sS * 16 + lo][c];

#pragma unroll
    for (int i = 0; i < 24; ++i) {
        int cc = i * 4 + cg;
        const float4* wr4 = (const float4*)&swi[cc * 32];
        float acc = sbi[cc];
#pragma unroll
        for (int c4 = 0; c4 < 8; ++c4) {
            float4 wv = wr4[c4];
            acc += xr[c4 * 4 + 0] * wv.x + xr[c4 * 4 + 1] * wv.y +
                   xr[c4 * 4 + 2] * wv.z + xr[c4 * 4 + 3] * wv.w;
        }
        sqkv[r * 100 + cc] = acc;
    }
    __syncthreads();

    // attention over 4 tracks: thread (la = tid>>4, h = (tid>>2)&3, ia = tid&3)
    {
        const int la = tid >> 4, h = (tid >> 2) & 3, ia = tid & 3;
        const float scale = 0.35355339059327373f;
        const float4* qp = (const float4*)&sqkv[(la * 4 + ia) * 100 + h * 8];
        float4 q0 = qp[0], q1 = qp[1];
        float sc[4];
        float mx = -1e30f;
#pragma unroll
        for (int jj = 0; jj < 4; ++jj) {
            const float4* kp = (const float4*)&sqkv[(la * 4 + jj) * 100 + 32 + h * 8];
            sc[jj] = dot8(q0, q1, kp[0], kp[1]) * scale;
            mx = fmaxf(mx, sc[jj]);
        }
        float den = 0.f;
#pragma unroll
        for (int jj = 0; jj < 4; ++jj) { sc[jj] = __expf(sc[jj] - mx); den += sc[jj]; }
        float inv = 1.f / den;
        float a[8];
#pragma unroll
        for (int dd = 0; dd < 8; ++dd) a[dd] = 0.f;
#pragma unroll
        for (int jj = 0; jj < 4; ++jj) {
            const float4* vp = (const float4*)&sqkv[(la * 4 + jj) * 100 + 64 + h * 8];
            float4 v0 = vp[0], v1 = vp[1];
            float wgt = sc[jj];
            a[0] += wgt * v0.x;  a[1] += wgt * v0.y;
            a[2] += wgt * v0.z;  a[3] += wgt * v0.w;
            a[4] += wgt * v1.x;  a[5] += wgt * v1.y;
            a[6] += wgt * v1.z;  a[7] += wgt * v1.w;
        }
#pragma unroll
        for (int dd = 0; dd < 8; ++dd) so[la * 4 + ia][h * 8 + dd] = a[dd] * inv;
    }
    __syncthreads();

    {
        float orow[32];
#pragma unroll
        for (int k = 0; k < 32; ++k) orow[k] = so[r][k];
#pragma unroll
        for (int i = 0; i < 8; ++i) {
            int c = i * 4 + cg;
            const float4* wr4 = (const float4*)&swo[c * 32];
            float acc = sbo[c] + xr[c];
#pragma unroll
            for (int k4 = 0; k4 < 8; ++k4) {
                float4 wv = wr4[k4];
                acc += orow[k4 * 4 + 0] * wv.x + orow[k4 * 4 + 1] * wv.y +
                       orow[k4 * 4 + 2] * wv.z + orow[k4 * 4 + 3] * wv.w;
            }
            sqkv[r * 100 + c] = acc;
        }
    }
    __syncthreads();

    if (tid < 64) {
        float mu = 0.f;
#pragma unroll
        for (int c = 0; c < 32; ++c) mu += sqkv[tid * 100 + c];
        mu *= (1.f / 32.f);
        float var = 0.f;
#pragma unroll
        for (int c = 0; c < 32; ++c) { float d = sqkv[tid * 100 + c] - mu; var += d * d; }
        var *= (1.f / 32.f);
        smean2[tid] = mu;
        srstd2[tid] = rsqrtf(var + LN_EPS);
    }
    __syncthreads();

    for (int pass = 0; pass < 2; ++pass) {
        int idx = pass * 256 + tid;      // 512 = 16 lo x 32 c
        int loo = idx >> 5, c = idx & 31;
        float acc = 0.f;
#pragma unroll
        for (int ss = 0; ss < 4; ++ss) {
            int rr = loo * 4 + ss;
            acc += (sqkv[rr * 100 + c] - smean2[rr]) * srstd2[rr];
        }
        float mval = 0.25f * acc * sg[c] + sb[c];
        m_out[(b * 64 + l0 + loo) * 32 + c] = mval;
        smv[loo][c] = mval * mval;
    }
    __syncthreads();

    if (tid < 16) {
        float sum = 0.f;
#pragma unroll
        for (int c = 0; c < 32; ++c) sum += smv[tid][c];
        nrm_out[b * 64 + l0 + tid] = sqrtf(sum);
    }
}

// ---------------------------------------------------------------------------
// Kernel 3 (v3): factorized outer-product + proj + LN + SiLU + transpose
// feat[b,i,j,cp] = (T_i[cp]·m_j)/(|m_i||m_j|) + pb;  T_i = pw·m_i
// 512 blocks (b x 8 i-chunks of 8) x 256 threads -> 2 blocks/CU.
// T phase rem-split: wave w owns rem = lane+128w (+64); pw slice cached in
// 64 regs (16 KB/wave global traffic); m rows via b128 broadcast from LDS.
// ---------------------------------------------------------------------------
__global__ __launch_bounds__(256) void k_pair(
    const float* __restrict__ m, const float* __restrict__ nrm,
    const float* __restrict__ pw, const float* __restrict__ pb,
    const float* __restrict__ pg, const float* __restrict__ pbeta,
    float* __restrict__ out)
{
    __shared__ float smj[64][36];       // stride 36 -> rows 16B-aligned
    __shared__ float sT[8 * 520];       // [il][rem], stride 520 (16B-aligned)
    __shared__ float snj[64];
    __shared__ float sbias[16], sgam[16], sbet[16];

    const int bx = blockIdx.x;          // 64 b x 8 i-chunks
    const int b  = bx >> 3;
    const int i0 = (bx & 7) * 8;
    const int tid = threadIdx.x;
    const int lane = tid & 63, w = tid >> 6;

    // preload this thread's two pw rem-rows into regs (global, coalesced, L2-hot)
    const int rem0 = lane + 128 * w;    // rem = cp*32+d, 0..511 over (w,lane)
    const int rem1 = rem0 + 64;
    const float* pw0 = pw + (rem0 >> 5) * 1024 + (rem0 & 31);
    const float* pw1 = pw + (rem1 >> 5) * 1024 + (rem1 & 31);
    float w0[32], w1[32];
#pragma unroll
    for (int c = 0; c < 32; ++c) { w0[c] = pw0[c * 32]; w1[c] = pw1[c * 32]; }

    const float* mb = m + b * 2048;
    for (int n = tid; n < 2048; n += 256) smj[n >> 5][n & 31] = mb[n];
    if (tid < 64) snj[tid] = nrm[b * 64 + tid];
    if (tid < 16) {
        sbias[tid] = pb[tid];
        sgam[tid]  = pg[tid];
        sbet[tid]  = pbeta[tid];
    }
    __syncthreads();

    // T phase: every thread computes T[il][rem0], T[il][rem1] for il = 0..7
#pragma unroll
    for (int il = 0; il < 8; ++il) {
        const float4* mr4 = (const float4*)&smj[i0 + il][0];  // b128 broadcast
        float a0 = 0.f, a1 = 0.f;
#pragma unroll
        for (int c4 = 0; c4 < 8; ++c4) {
            float4 mv = mr4[c4];
            a0 += mv.x * w0[c4 * 4 + 0] + mv.y * w0[c4 * 4 + 1] +
                  mv.z * w0[c4 * 4 + 2] + mv.w * w0[c4 * 4 + 3];
            a1 += mv.x * w1[c4 * 4 + 0] + mv.y * w1[c4 * 4 + 1] +
                  mv.z * w1[c4 * 4 + 2] + mv.w * w1[c4 * 4 + 3];
        }
        sT[il * 520 + rem0] = a0;       // lane-distinct banks, conflict-free
        sT[il * 520 + rem1] = a1;
    }
    __syncthreads();

    // out phase: lane = j; wave w handles il = 2w, 2w+1
    const int j = lane;
    float mj[32];
    {
        const float4* mjp = (const float4*)&smj[j][0];
#pragma unroll
        for (int d4 = 0; d4 < 8; ++d4) {
            float4 t = mjp[d4];
            mj[d4 * 4 + 0] = t.x;  mj[d4 * 4 + 1] = t.y;
            mj[d4 * 4 + 2] = t.z;  mj[d4 * 4 + 3] = t.w;
        }
    }
    const float nj = snj[j];

#pragma unroll
    for (int q = 0; q < 2; ++q) {
        const int il = w * 2 + q;
        const int ig = i0 + il;
        const float invn = 1.f / fmaxf(snj[ig] * nj, 1e-6f);
        float f[16];
#pragma unroll
        for (int cp = 0; cp < 16; ++cp) {
            const float4* tr = (const float4*)&sT[il * 520 + cp * 32]; // b128 bcast
            float acc = 0.f;
#pragma unroll
            for (int d4 = 0; d4 < 8; ++d4) {
                float4 tv = tr[d4];
                acc += tv.x * mj[d4 * 4 + 0] + tv.y * mj[d4 * 4 + 1] +
                       tv.z * mj[d4 * 4 + 2] + tv.w * mj[d4 * 4 + 3];
            }
            f[cp] = acc * invn + sbias[cp];
        }
        float mu = 0.f;
#pragma unroll
        for (int cp = 0; cp < 16; ++cp) mu += f[cp];
        mu *= (1.f / 16.f);
        float var = 0.f;
#pragma unroll
        for (int cp = 0; cp < 16; ++cp) { float d = f[cp] - mu; var += d * d; }
        var *= (1.f / 16.f);
        const float rstd = rsqrtf(var + LN_EPS);
#pragma unroll
        for (int cp = 0; cp < 16; ++cp) {
            float v = (f[cp] - mu) * rstd * sgam[cp] + sbet[cp];
            float sl = v / (1.f + __expf(-v));
            out[((b * 16 + cp) * 64 + ig) * 64 + j] = sl;
        }
    }
}

// ---------------------------------------------------------------------------
extern "C" void kernel_launch(void* const* d_in, const int* in_sizes, int n_in,
                              void* d_out, int out_size, void* d_ws, size_t ws_size,
                              hipStream_t stream) {
    const float* ctcf  = (const float*)d_in[0];
    const float* hac   = (const float*)d_in[1];
    const float* me1   = (const float*)d_in[2];
    const float* me3   = (const float*)d_in[3];
    const float* ew    = (const float*)d_in[4];
    const float* ebias = (const float*)d_in[5];
    const float* pe    = (const float*)d_in[6];
    const float* riw   = (const float*)d_in[7];
    const float* rib   = (const float*)d_in[8];
    const float* row_  = (const float*)d_in[9];
    const float* rob   = (const float*)d_in[10];
    const float* rlg   = (const float*)d_in[11];
    const float* rlb   = (const float*)d_in[12];
    const float* ciw   = (const float*)d_in[13];
    const float* cib   = (const float*)d_in[14];
    const float* cow   = (const float*)d_in[15];
    const float* cob   = (const float*)d_in[16];
    const float* clg   = (const float*)d_in[17];
    const float* clb   = (const float*)d_in[18];
    const float* pw    = (const float*)d_in[19];
    const float* pb    = (const float*)d_in[20];
    const float* pg    = (const float*)d_in[21];
    const float* pbt   = (const float*)d_in[22];

    float* out = (float*)d_out;

    // msaR (2 MB) borrows d_out (16 MB f32): fully consumed by k_col before
    // k_pair writes out (serial stream). m + norms in ws (~528 KB).
    float* msaR = (float*)d_out;
    float* mbuf = (float*)d_ws;                  // 64*64*32 floats
    float* nbuf = mbuf + 64 * 64 * 32;           // 64*64 floats

    k_row<<<256, 256, 0, stream>>>(ctcf, hac, me1, me3, ew, ebias, pe,
                                   riw, rib, row_, rob, rlg, rlb, msaR);
    k_col<<<256, 256, 0, stream>>>(msaR, ciw, cib, cow, cob, clg, clb,
                                   mbuf, nbuf);
    k_pair<<<512, 256, 0, stream>>>(mbuf, nbuf, pw, pb, pg, pbt, out);
}

// Round 8
// 154.943 us; speedup vs baseline: 1.0834x; 1.0132x over previous
//
#include <hip/hip_runtime.h>
#include <hip/hip_bf16.h>

#define LN_EPS 1e-5f

__device__ __forceinline__ float dot8(float4 a0, float4 a1, float4 b0, float4 b1) {
    return a0.x * b0.x + a0.y * b0.y + a0.z * b0.z + a0.w * b0.w +
           a1.x * b1.x + a1.y * b1.y + a1.z * b1.z + a1.w * b1.w;
}

// ---------------------------------------------------------------------------
// Kernel 1: embed + pos + row attention (64 bins) + residual + LN
// one block per (b, s): 256 blocks x 256 threads
// Weights are read DIRECTLY from global (wave-uniform -> one 16B L1/L2 req
// per instr on the vector-mem pipe), keeping the DS pipe for token data.
// ---------------------------------------------------------------------------
__global__ __launch_bounds__(256) void k_row(
    const float* __restrict__ ctcf, const float* __restrict__ hac,
    const float* __restrict__ me1,  const float* __restrict__ me3,
    const float* __restrict__ ew,   const float* __restrict__ eb,
    const float* __restrict__ pe,
    const float* __restrict__ w_in, const float* __restrict__ b_in,
    const float* __restrict__ w_out,const float* __restrict__ b_out,
    const float* __restrict__ ln_g, const float* __restrict__ ln_b,
    float* __restrict__ msaR)
{
    __shared__ float sx[64][33];        // x tile (residual source)
    __shared__ float sqkv[64 * 100];    // qkv rows, stride 100 (16B-aligned)
    __shared__ float so[64][33];        // attention output
    __shared__ float smean[64], srstd[64];

    const int blk = blockIdx.x;          // b*4 + s
    const int s   = blk & 3;
    const int b   = blk >> 2;
    const int tid = threadIdx.x;

    const float* chip = (s == 0) ? ctcf : (s == 1) ? hac : (s == 2) ? me1 : me3;

    for (int n = tid; n < 2048; n += 256) {
        int l = n >> 5, c = n & 31;
        sx[l][c] = chip[b * 64 + l] * ew[c] + eb[c] + pe[l * 32 + c];
    }
    __syncthreads();

    const int l  = tid & 63;
    const int cg = tid >> 6;             // wave id -> wave-uniform

    float xr[32];
#pragma unroll
    for (int c = 0; c < 32; ++c) xr[c] = sx[l][c];

    // qkv[l][cc] = x[l]·w_in[cc] + b_in[cc]; w row read from global (uniform)
#pragma unroll
    for (int i = 0; i < 24; ++i) {
        int cc = i * 4 + cg;
        const float4* wr4 = (const float4*)&w_in[cc * 32];
        float acc = b_in[cc];
#pragma unroll
        for (int c4 = 0; c4 < 8; ++c4) {
            float4 wv = wr4[c4];
            acc += xr[c4 * 4 + 0] * wv.x + xr[c4 * 4 + 1] * wv.y +
                   xr[c4 * 4 + 2] * wv.z + xr[c4 * 4 + 3] * wv.w;
        }
        sqkv[l * 100 + cc] = acc;
    }
    __syncthreads();

    // attention: thread (h = cg, l); online softmax; K/V rows b128 broadcast
    {
        const int h = cg;
        const float4* qp = (const float4*)&sqkv[l * 100 + h * 8];
        float4 q0 = qp[0], q1 = qp[1];
        const float scale = 0.35355339059327373f;  // 1/sqrt(8)
        float mrun = -1e30f, denom = 0.f, a[8];
#pragma unroll
        for (int dd = 0; dd < 8; ++dd) a[dd] = 0.f;
        for (int j = 0; j < 64; ++j) {
            const float4* kp = (const float4*)&sqkv[j * 100 + 32 + h * 8];
            float4 k0 = kp[0], k1 = kp[1];
            float sc = dot8(q0, q1, k0, k1) * scale;
            const float4* vp = (const float4*)&sqkv[j * 100 + 64 + h * 8];
            float4 v0 = vp[0], v1 = vp[1];
            float mnew = fmaxf(mrun, sc);
            float corr = __expf(mrun - mnew);
            float w = __expf(sc - mnew);
            denom = denom * corr + w;
            a[0] = a[0] * corr + w * v0.x;  a[1] = a[1] * corr + w * v0.y;
            a[2] = a[2] * corr + w * v0.z;  a[3] = a[3] * corr + w * v0.w;
            a[4] = a[4] * corr + w * v1.x;  a[5] = a[5] * corr + w * v1.y;
            a[6] = a[6] * corr + w * v1.z;  a[7] = a[7] * corr + w * v1.w;
            mrun = mnew;
        }
        float inv = 1.f / denom;
#pragma unroll
        for (int dd = 0; dd < 8; ++dd) so[l][h * 8 + dd] = a[dd] * inv;
    }
    __syncthreads();

    // out proj + residual -> sqkv cols 0..31 (w row from global, uniform)
    {
        float orow[32];
#pragma unroll
        for (int k = 0; k < 32; ++k) orow[k] = so[l][k];
#pragma unroll
        for (int i = 0; i < 8; ++i) {
            int c = i * 4 + cg;
            const float4* wr4 = (const float4*)&w_out[c * 32];
            float acc = b_out[c] + xr[c];
#pragma unroll
            for (int k4 = 0; k4 < 8; ++k4) {
                float4 wv = wr4[k4];
                acc += orow[k4 * 4 + 0] * wv.x + orow[k4 * 4 + 1] * wv.y +
                       orow[k4 * 4 + 2] * wv.z + orow[k4 * 4 + 3] * wv.w;
            }
            sqkv[l * 100 + c] = acc;
        }
    }
    __syncthreads();

    if (tid < 64) {
        float mu = 0.f;
#pragma unroll
        for (int c = 0; c < 32; ++c) mu += sqkv[tid * 100 + c];
        mu *= (1.f / 32.f);
        float var = 0.f;
#pragma unroll
        for (int c = 0; c < 32; ++c) { float d = sqkv[tid * 100 + c] - mu; var += d * d; }
        var *= (1.f / 32.f);
        smean[tid] = mu;
        srstd[tid] = rsqrtf(var + LN_EPS);
    }
    __syncthreads();

    float* outp = msaR + blk * 2048;     // (B,S,Lb,C)
    for (int n = tid; n < 2048; n += 256) {
        int ll = n >> 5, c = n & 31;
        outp[n] = (sqkv[ll * 100 + c] - smean[ll]) * srstd[ll] * ln_g[c] + ln_b[c];
    }
}

// ---------------------------------------------------------------------------
// Kernel 2: column attention (4 tracks) + residual + LN + track mean + norm
// one block per (b, 16-bin chunk): 256 blocks x 256 threads
// Weights read directly from global (wave-uniform), token data in LDS.
// ---------------------------------------------------------------------------
__global__ __launch_bounds__(256) void k_col(
    const float* __restrict__ msaR,
    const float* __restrict__ w_in, const float* __restrict__ b_in,
    const float* __restrict__ w_out,const float* __restrict__ b_out,
    const float* __restrict__ ln_g, const float* __restrict__ ln_b,
    float* __restrict__ m_out, float* __restrict__ nrm_out)
{
    __shared__ float sx[64][33];        // rows keyed s*16+lo
    __shared__ float sqkv[64 * 100];    // rows keyed r = lo*4+s
    __shared__ float so[64][33];        // rows keyed r
    __shared__ float smean2[64], srstd2[64];
    __shared__ float smv[16][33];

    const int bx = blockIdx.x;           // 64 b x 4 chunks
    const int b  = bx >> 2;
    const int l0 = (bx & 3) * 16;
    const int tid = threadIdx.x;

    for (int n = tid; n < 2048; n += 256) {
        int s = n >> 9, lo = (n >> 5) & 15, c = n & 31;
        sx[s * 16 + lo][c] = msaR[((b * 4 + s) * 64 + l0 + lo) * 32 + c];
    }
    __syncthreads();

    const int r  = tid & 63;
    const int sS = r & 3, lo = r >> 2;
    const int cg = tid >> 6;

    float xr[32];
#pragma unroll
    for (int c = 0; c < 32; ++c) xr[c] = sx[sS * 16 + lo][c];

#pragma unroll
    for (int i = 0; i < 24; ++i) {
        int cc = i * 4 + cg;
        const float4* wr4 = (const float4*)&w_in[cc * 32];
        float acc = b_in[cc];
#pragma unroll
        for (int c4 = 0; c4 < 8; ++c4) {
            float4 wv = wr4[c4];
            acc += xr[c4 * 4 + 0] * wv.x + xr[c4 * 4 + 1] * wv.y +
                   xr[c4 * 4 + 2] * wv.z + xr[c4 * 4 + 3] * wv.w;
        }
        sqkv[r * 100 + cc] = acc;
    }
    __syncthreads();

    // attention over 4 tracks: thread (la = tid>>4, h = (tid>>2)&3, ia = tid&3)
    {
        const int la = tid >> 4, h = (tid >> 2) & 3, ia = tid & 3;
        const float scale = 0.35355339059327373f;
        const float4* qp = (const float4*)&sqkv[(la * 4 + ia) * 100 + h * 8];
        float4 q0 = qp[0], q1 = qp[1];
        float sc[4];
        float mx = -1e30f;
#pragma unroll
        for (int jj = 0; jj < 4; ++jj) {
            const float4* kp = (const float4*)&sqkv[(la * 4 + jj) * 100 + 32 + h * 8];
            sc[jj] = dot8(q0, q1, kp[0], kp[1]) * scale;
            mx = fmaxf(mx, sc[jj]);
        }
        float den = 0.f;
#pragma unroll
        for (int jj = 0; jj < 4; ++jj) { sc[jj] = __expf(sc[jj] - mx); den += sc[jj]; }
        float inv = 1.f / den;
        float a[8];
#pragma unroll
        for (int dd = 0; dd < 8; ++dd) a[dd] = 0.f;
#pragma unroll
        for (int jj = 0; jj < 4; ++jj) {
            const float4* vp = (const float4*)&sqkv[(la * 4 + jj) * 100 + 64 + h * 8];
            float4 v0 = vp[0], v1 = vp[1];
            float wgt = sc[jj];
            a[0] += wgt * v0.x;  a[1] += wgt * v0.y;
            a[2] += wgt * v0.z;  a[3] += wgt * v0.w;
            a[4] += wgt * v1.x;  a[5] += wgt * v1.y;
            a[6] += wgt * v1.z;  a[7] += wgt * v1.w;
        }
#pragma unroll
        for (int dd = 0; dd < 8; ++dd) so[la * 4 + ia][h * 8 + dd] = a[dd] * inv;
    }
    __syncthreads();

    {
        float orow[32];
#pragma unroll
        for (int k = 0; k < 32; ++k) orow[k] = so[r][k];
#pragma unroll
        for (int i = 0; i < 8; ++i) {
            int c = i * 4 + cg;
            const float4* wr4 = (const float4*)&w_out[c * 32];
            float acc = b_out[c] + xr[c];
#pragma unroll
            for (int k4 = 0; k4 < 8; ++k4) {
                float4 wv = wr4[k4];
                acc += orow[k4 * 4 + 0] * wv.x + orow[k4 * 4 + 1] * wv.y +
                       orow[k4 * 4 + 2] * wv.z + orow[k4 * 4 + 3] * wv.w;
            }
            sqkv[r * 100 + c] = acc;
        }
    }
    __syncthreads();

    if (tid < 64) {
        float mu = 0.f;
#pragma unroll
        for (int c = 0; c < 32; ++c) mu += sqkv[tid * 100 + c];
        mu *= (1.f / 32.f);
        float var = 0.f;
#pragma unroll
        for (int c = 0; c < 32; ++c) { float d = sqkv[tid * 100 + c] - mu; var += d * d; }
        var *= (1.f / 32.f);
        smean2[tid] = mu;
        srstd2[tid] = rsqrtf(var + LN_EPS);
    }
    __syncthreads();

    for (int pass = 0; pass < 2; ++pass) {
        int idx = pass * 256 + tid;      // 512 = 16 lo x 32 c
        int loo = idx >> 5, c = idx & 31;
        float acc = 0.f;
#pragma unroll
        for (int ss = 0; ss < 4; ++ss) {
            int rr = loo * 4 + ss;
            acc += (sqkv[rr * 100 + c] - smean2[rr]) * srstd2[rr];
        }
        float mval = 0.25f * acc * ln_g[c] + ln_b[c];
        m_out[(b * 64 + l0 + loo) * 32 + c] = mval;
        smv[loo][c] = mval * mval;
    }
    __syncthreads();

    if (tid < 16) {
        float sum = 0.f;
#pragma unroll
        for (int c = 0; c < 32; ++c) sum += smv[tid][c];
        nrm_out[b * 64 + l0 + tid] = sqrtf(sum);
    }
}

// ---------------------------------------------------------------------------
// Kernel 3 (v3): factorized outer-product + proj + LN + SiLU + transpose
// feat[b,i,j,cp] = (T_i[cp]·m_j)/(|m_i||m_j|) + pb;  T_i = pw·m_i
// 512 blocks (b x 8 i-chunks of 8) x 256 threads -> 2 blocks/CU.
// T phase rem-split: wave w owns rem = lane+128w (+64); pw slice cached in
// 64 regs (16 KB/wave global traffic); m rows via b128 broadcast from LDS.
// ---------------------------------------------------------------------------
__global__ __launch_bounds__(256) void k_pair(
    const float* __restrict__ m, const float* __restrict__ nrm,
    const float* __restrict__ pw, const float* __restrict__ pb,
    const float* __restrict__ pg, const float* __restrict__ pbeta,
    float* __restrict__ out)
{
    __shared__ float smj[64][36];       // stride 36 -> rows 16B-aligned
    __shared__ float sT[8 * 520];       // [il][rem], stride 520 (16B-aligned)
    __shared__ float snj[64];
    __shared__ float sbias[16], sgam[16], sbet[16];

    const int bx = blockIdx.x;          // 64 b x 8 i-chunks
    const int b  = bx >> 3;
    const int i0 = (bx & 7) * 8;
    const int tid = threadIdx.x;
    const int lane = tid & 63, w = tid >> 6;

    // preload this thread's two pw rem-rows into regs (global, coalesced, L2-hot)
    const int rem0 = lane + 128 * w;    // rem = cp*32+d, 0..511 over (w,lane)
    const int rem1 = rem0 + 64;
    const float* pw0 = pw + (rem0 >> 5) * 1024 + (rem0 & 31);
    const float* pw1 = pw + (rem1 >> 5) * 1024 + (rem1 & 31);
    float w0[32], w1[32];
#pragma unroll
    for (int c = 0; c < 32; ++c) { w0[c] = pw0[c * 32]; w1[c] = pw1[c * 32]; }

    const float* mb = m + b * 2048;
    for (int n = tid; n < 2048; n += 256) smj[n >> 5][n & 31] = mb[n];
    if (tid < 64) snj[tid] = nrm[b * 64 + tid];
    if (tid < 16) {
        sbias[tid] = pb[tid];
        sgam[tid]  = pg[tid];
        sbet[tid]  = pbeta[tid];
    }
    __syncthreads();

    // T phase: every thread computes T[il][rem0], T[il][rem1] for il = 0..7
#pragma unroll
    for (int il = 0; il < 8; ++il) {
        const float4* mr4 = (const float4*)&smj[i0 + il][0];  // b128 broadcast
        float a0 = 0.f, a1 = 0.f;
#pragma unroll
        for (int c4 = 0; c4 < 8; ++c4) {
            float4 mv = mr4[c4];
            a0 += mv.x * w0[c4 * 4 + 0] + mv.y * w0[c4 * 4 + 1] +
                  mv.z * w0[c4 * 4 + 2] + mv.w * w0[c4 * 4 + 3];
            a1 += mv.x * w1[c4 * 4 + 0] + mv.y * w1[c4 * 4 + 1] +
                  mv.z * w1[c4 * 4 + 2] + mv.w * w1[c4 * 4 + 3];
        }
        sT[il * 520 + rem0] = a0;       // lane-distinct banks, conflict-free
        sT[il * 520 + rem1] = a1;
    }
    __syncthreads();

    // out phase: lane = j; wave w handles il = 2w, 2w+1
    const int j = lane;
    float mj[32];
    {
        const float4* mjp = (const float4*)&smj[j][0];
#pragma unroll
        for (int d4 = 0; d4 < 8; ++d4) {
            float4 t = mjp[d4];
            mj[d4 * 4 + 0] = t.x;  mj[d4 * 4 + 1] = t.y;
            mj[d4 * 4 + 2] = t.z;  mj[d4 * 4 + 3] = t.w;
        }
    }
    const float nj = snj[j];

#pragma unroll
    for (int q = 0; q < 2; ++q) {
        const int il = w * 2 + q;
        const int ig = i0 + il;
        const float invn = 1.f / fmaxf(snj[ig] * nj, 1e-6f);
        float f[16];
#pragma unroll
        for (int cp = 0; cp < 16; ++cp) {
            const float4* tr = (const float4*)&sT[il * 520 + cp * 32]; // b128 bcast
            float acc = 0.f;
#pragma unroll
            for (int d4 = 0; d4 < 8; ++d4) {
                float4 tv = tr[d4];
                acc += tv.x * mj[d4 * 4 + 0] + tv.y * mj[d4 * 4 + 1] +
                       tv.z * mj[d4 * 4 + 2] + tv.w * mj[d4 * 4 + 3];
            }
            f[cp] = acc * invn + sbias[cp];
        }
        float mu = 0.f;
#pragma unroll
        for (int cp = 0; cp < 16; ++cp) mu += f[cp];
        mu *= (1.f / 16.f);
        float var = 0.f;
#pragma unroll
        for (int cp = 0; cp < 16; ++cp) { float d = f[cp] - mu; var += d * d; }
        var *= (1.f / 16.f);
        const float rstd = rsqrtf(var + LN_EPS);
#pragma unroll
        for (int cp = 0; cp < 16; ++cp) {
            float v = (f[cp] - mu) * rstd * sgam[cp] + sbet[cp];
            float sl = v / (1.f + __expf(-v));
            out[((b * 16 + cp) * 64 + ig) * 64 + j] = sl;
        }
    }
}

// ---------------------------------------------------------------------------
extern "C" void kernel_launch(void* const* d_in, const int* in_sizes, int n_in,
                              void* d_out, int out_size, void* d_ws, size_t ws_size,
                              hipStream_t stream) {
    const float* ctcf  = (const float*)d_in[0];
    const float* hac   = (const float*)d_in[1];
    const float* me1   = (const float*)d_in[2];
    const float* me3   = (const float*)d_in[3];
    const float* ew    = (const float*)d_in[4];
    const float* ebias = (const float*)d_in[5];
    const float* pe    = (const float*)d_in[6];
    const float* riw   = (const float*)d_in[7];
    const float* rib   = (const float*)d_in[8];
    const float* row_  = (const float*)d_in[9];
    const float* rob   = (const float*)d_in[10];
    const float* rlg   = (const float*)d_in[11];
    const float* rlb   = (const float*)d_in[12];
    const float* ciw   = (const float*)d_in[13];
    const float* cib   = (const float*)d_in[14];
    const float* cow   = (const float*)d_in[15];
    const float* cob   = (const float*)d_in[16];
    const float* clg   = (const float*)d_in[17];
    const float* clb   = (const float*)d_in[18];
    const float* pw    = (const float*)d_in[19];
    const float* pb    = (const float*)d_in[20];
    const float* pg    = (const float*)d_in[21];
    const float* pbt   = (const float*)d_in[22];

    float* out = (float*)d_out;

    // msaR (2 MB) borrows d_out (16 MB f32): fully consumed by k_col before
    // k_pair writes out (serial stream). m + norms in ws (~528 KB).
    float* msaR = (float*)d_out;
    float* mbuf = (float*)d_ws;                  // 64*64*32 floats
    float* nbuf = mbuf + 64 * 64 * 32;           // 64*64 floats

    k_row<<<256, 256, 0, stream>>>(ctcf, hac, me1, me3, ew, ebias, pe,
                                   riw, rib, row_, rob, rlg, rlb, msaR);
    k_col<<<256, 256, 0, stream>>>(msaR, ciw, cib, cow, cob, clg, clb,
                                   mbuf, nbuf);
    k_pair<<<512, 256, 0, stream>>>(mbuf, nbuf, pw, pb, pg, pbt, out);
}